// Round 4
// baseline (94644.922 us; speedup 1.0000x reference)
//
#include <hip/hip_runtime.h>
#include <hip/hip_bf16.h>
#include <math.h>

// ============================================================================
// RNNDecoder v6: v5 structure + per-step FENCE-FREE pacing barrier.
// 128 independent persistent blocks (one row each). The v5 post-mortem showed
// ~3000 L2 misses/CU/step from blocks drifting out of phase (16 CUs/XCD sweep
// the same 2.6 MB weight set at different offsets -> LRU churn). v6 re-locks
// the blocks every step with RELAXED agent-scope atomics (coherence-point RMW
// arrive + atomic-load poll, bounded spin): no acquire/release, hence no
// buffer_inv/wbl2 L2 nukes (the v3 mistake). All arithmetic is byte-identical
// to v5 (same passing argmax trajectory).
// ============================================================================

typedef unsigned short u16;
typedef unsigned int u32;
typedef float f4 __attribute__((ext_vector_type(4)));
typedef u32 u4 __attribute__((ext_vector_type(4)));

#define NB 128
#define NT 1024
#define Ln 500
#define Hn 512
#define LDn 256
#define UDn 128
#define Vn 33
#define Tn 500
#define SENT_V 0x9E3779B1u

// ---- workspace u32 offsets ----
#define W_INITC 0u
#define W_SENT  1u
#define W_GEM   64u        // f32 [33][1536]   embed@W_ih^T + b_ih
#define W_M2    50752u     // f32 [512 j][128 u] catW_right@memW
#define W_CB    116288u    // f32 [512]        cat_b + catWr@mem_b
#define W_PACE  116800u    // u32 [512] per-step pacing counters
#define W_END   117312u    // ~470 KB

__device__ __forceinline__ float b2f(u16 v) {
  u32 x = ((u32)v) << 16; float f; __builtin_memcpy(&f, &x, 4); return f;
}
__device__ __forceinline__ float bitsf(u32 x) {
  float f; __builtin_memcpy(&f, &x, 4); return f;
}
#define LO16(d) bitsf((u32)(d) << 16)
#define HI16(d) bitsf((u32)(d) & 0xffff0000u)
__device__ __forceinline__ u16 f2b(float f) {  // RNE
  u32 x; __builtin_memcpy(&x, &f, 4);
  x += 0x7fffu + ((x >> 16) & 1u);
  return (u16)(x >> 16);
}
// mode==1: buffer holds bf16; mode==0: fp32
__device__ __forceinline__ float ldv(const void* p, size_t i, int mode) {
  return mode ? b2f(((const u16*)p)[i]) : ((const float*)p)[i];
}
__device__ __forceinline__ u32 aload(u32* p) {
  return __hip_atomic_load(p, __ATOMIC_ACQUIRE, __HIP_MEMORY_SCOPE_AGENT);
}
__device__ __forceinline__ void waitGe(u32* p, u32 tgt) {
  while (aload(p) < tgt) __builtin_amdgcn_s_sleep(4);
}
__device__ __forceinline__ void arrive(u32* p) {
  __hip_atomic_fetch_add(p, 1u, __ATOMIC_RELEASE, __HIP_MEMORY_SCOPE_AGENT);
}
__device__ __forceinline__ void astore(u32* p, u32 v) {
  __hip_atomic_store(p, v, __ATOMIC_RELEASE, __HIP_MEMORY_SCOPE_AGENT);
}
// ---- fence-free pacing primitives (no L2 cache maintenance) ----
__device__ __forceinline__ void pace_zero(u32* p) {
  __hip_atomic_store(p, 0u, __ATOMIC_RELAXED, __HIP_MEMORY_SCOPE_AGENT);
}
__device__ __forceinline__ void pace_add(u32* p) {
  __hip_atomic_fetch_add(p, 1u, __ATOMIC_RELAXED, __HIP_MEMORY_SCOPE_AGENT);
}
__device__ __forceinline__ u32 pace_ld(u32* p) {
  return __hip_atomic_load(p, __ATOMIC_RELAXED, __HIP_MEMORY_SCOPE_AGENT);
}

extern "C" __global__ void __launch_bounds__(1024)
rnn_v6(const void* latent, const void* ulat, const void* embd,
       const void* hidW, const void* hidb, const void* memW, const void* memb,
       const void* Wih, const void* Whh, const void* bih, const void* bhh,
       const void* catW, const void* catb, const void* outW, const void* outb,
       void* out, u32* ws) {
  // ---- LDS: per-row persistent state + phase-local arena ----
  __shared__ __align__(16) u16  ulat_l[Ln * 130];  // 130000 B (mode1 only)
  __shared__ __align__(16) float h_l[Hn];          // 2048 B, live 500 steps
  __shared__ __align__(16) char  arena[12288];     // phase-local scratch
  __shared__ __align__(16) float bhh_l[1536];      // 6144 B
  __shared__ float misc_l[2];                      // [0]=s0 [1]=inv_sum
  __shared__ int   s_tok;
  __shared__ u32   s_det;

  const int tid = threadIdx.x, blk = blockIdx.x;
  const int wv = tid >> 6, lane = tid & 63;
  const int gtid = blk * NT + tid;

  // ---- dtype detection: embed row PAD=1 is zero iff bf16 (verbatim) ----
  if (tid == 0) s_det = 0u;
  __syncthreads();
  if (tid < 256) {
    u32 v = ((const u32*)embd)[256 + tid];
    if (v) atomicOr(&s_det, 1u);
  }
  __syncthreads();
  const int mode = (s_det == 0u) ? 1 : 0;

  float* GEM = (float*)(ws + W_GEM);
  float* M2  = (float*)(ws + W_M2);
  float* cbF = (float*)(ws + W_CB);

  // ---- arena views (byte offsets; phases barrier-separated) ----
  float* ghq   = (float*)arena;            // GRU: [1536] dot+bhh      6144 B
  float* ps    = (float*)arena;            // attn: [128]              [0,512)
  float* ss    = (float*)(arena + 512);    // attn: [500]              [512,2512)
  float* es    = (float*)(arena + 2560);   // attn: [500]
  float* Bpart = (float*)(arena + 4608);   // attn: [8][128]           [4608,8704)
  float* cuv   = (float*)(arena + 8704);   // attn: [128]              [8704,9216)
  float* ccp2  = (float*)arena;            // cc:  [512][2]            [0,4096)
  float* ccs   = (float*)(arena + 4608);   // cc:  [512]               [4608,6656)
  float* lgs   = (float*)(arena + 6656);   // log: [16*34]             [6656,8832)

  // ======================= per-block private init ===========================
  if (mode) {  // row's ulat tile -> LDS (padded stride 130 for bank spread)
    const u16* src = (const u16*)ulat + (size_t)blk * Ln * UDn;
    for (int i = tid; i < Ln * UDn; i += NT) {
      int l = i >> 7, c = i & 127;
      ulat_l[l * 130 + c] = src[(size_t)l * UDn + c];
    }
  }
  for (int i = tid; i < 1536; i += NT) bhh_l[i] = ldv(bhh, i, mode);
  if (tid < Hn) {  // h0 = latent @ hidW^T + hidb  (v4-exact order)
    int k = tid;
    float a = ldv(hidb, k, mode);
    for (int q = 0; q < LDn; q++)
      a += ldv(latent, (size_t)blk * LDn + q, mode) * ldv(hidW, (size_t)k * LDn + q, mode);
    h_l[k] = a;
  }
  if (tid == 0) s_tok = 0;  // SOS

  // ======================= cooperative ws table build =======================
  if (gtid < 512) pace_zero(ws + W_PACE + gtid);       // coherence-point zero
  if (gtid < 50688) {                                  // GEM = embed@Wih^T+bih
    int v = gtid / 1536, j = gtid - v * 1536;
    float a = ldv(bih, j, mode);
    for (int k = 0; k < Hn; k++)
      a += ldv(embd, (size_t)v * Hn + k, mode) * ldv(Wih, (size_t)j * Hn + k, mode);
    GEM[gtid] = a;
  }
  if (gtid < 65536) {                                  // M2[j][u] = catWr@memW
    int j = gtid >> 7, u = gtid & 127;
    float a = 0.f;
    for (int h = 0; h < Hn; h++)
      a += ldv(catW, (size_t)j * 1024 + 512 + h, mode) * ldv(memW, (size_t)h * UDn + u, mode);
    M2[(size_t)j * 128 + u] = a;
  }
  if (gtid >= 65536 && gtid < 66048) {                 // cbias
    int j = gtid - 65536;
    float a = ldv(catb, j, mode);
    for (int h = 0; h < Hn; h++)
      a += ldv(catW, (size_t)j * 1024 + 512 + h, mode) * ldv(memb, h, mode);
    cbF[j] = a;
  }
  __threadfence();
  __syncthreads();
  if (tid == 0) {  // poison-agnostic device barrier (proven pattern)
    if (blk == 0) {
      __hip_atomic_store(ws + W_INITC, 0u, __ATOMIC_RELAXED, __HIP_MEMORY_SCOPE_AGENT);
      astore(ws + W_SENT, SENT_V);
    }
    while (aload(ws + W_SENT) != SENT_V) __builtin_amdgcn_s_sleep(8);
    arrive(ws + W_INITC);
    waitGe(ws + W_INITC, NB);
  }
  __syncthreads();

  // ======================= 500 decode steps =================================
  for (int t = 0; t < Tn; t++) {
    // ---- fence-free pacing barrier: keep the 128 blocks phase-locked so the
    // shared 2.6 MB weight sweep stays L2-resident per XCD. Pure pacing: no
    // ordering semantics needed (blocks are data-independent), bounded spin
    // guarantees forward progress in any state.
    if (t > 0 && tid == 0) {
      u32* pc = ws + W_PACE + (t - 1);
      pace_add(pc);  // "I finished step t-1"
      u32 it = 0;
      while (pace_ld(pc) < (u32)NB && ++it < 1024u)
        __builtin_amdgcn_s_sleep(1);
    }
    __syncthreads();  // s_tok + prev-step arena reads complete + pacing

    // ---- GRU dots: lane (r,c) = (row-in-group, chunk). Each lane computes
    // v4's exact chunk-c accumulation (descending fma nest, k4 ascending);
    // chunk partials folded strictly left-to-right via shfl (== v4's s+=a_c).
    {
      const int r = lane >> 3, c = lane & 7;
      f4 xv[16];  // this lane's h slice: chunk c = h[c*64 .. c*64+64)
#pragma unroll
      for (int i = 0; i < 16; i++) xv[i] = *(const f4*)(h_l + c * 64 + i * 4);
      const int base = lane & 56;
      if (mode) {
        for (int g = 0; g < 12; g++) {
          const int d = wv * 96 + g * 8 + r;
          const u4* wp = (const u4*)Whh + (size_t)d * 64 + c * 8;
          float a = 0.f;
#pragma unroll
          for (int b = 0; b < 2; b++) {
            u4 q[4];
#pragma unroll
            for (int s2 = 0; s2 < 4; s2++) q[s2] = wp[b * 4 + s2];
#pragma unroll
            for (int s2 = 0; s2 < 4; s2++) {
              const f4 xa = xv[b * 8 + s2 * 2], xb = xv[b * 8 + s2 * 2 + 1];
              a = fmaf(LO16(q[s2].x), xa.x, fmaf(HI16(q[s2].x), xa.y,
                  fmaf(LO16(q[s2].y), xa.z, fmaf(HI16(q[s2].y), xa.w, a))));
              a = fmaf(LO16(q[s2].z), xb.x, fmaf(HI16(q[s2].z), xb.y,
                  fmaf(LO16(q[s2].w), xb.z, fmaf(HI16(q[s2].w), xb.w, a))));
            }
          }
          float s = __shfl(a, base);
#pragma unroll
          for (int c2 = 1; c2 < 8; c2++) s += __shfl(a, base + c2);
          if (c == 0) ghq[d] = s + bhh_l[d];
        }
      } else {
        for (int g = 0; g < 12; g++) {
          const int d = wv * 96 + g * 8 + r;
          const f4* wp = (const f4*)Whh + (size_t)d * 128 + c * 16;
          float a = 0.f;
#pragma unroll
          for (int b = 0; b < 4; b++) {
            f4 q[4];
#pragma unroll
            for (int s2 = 0; s2 < 4; s2++) q[s2] = wp[b * 4 + s2];
#pragma unroll
            for (int s2 = 0; s2 < 4; s2++) {
              const f4 xa = xv[b * 4 + s2];
              a = fmaf(q[s2].x, xa.x, fmaf(q[s2].y, xa.y,
                  fmaf(q[s2].z, xa.z, fmaf(q[s2].w, xa.w, a))));
            }
          }
          float s = __shfl(a, base);
#pragma unroll
          for (int c2 = 1; c2 < 8; c2++) s += __shfl(a, base + c2);
          if (c == 0) ghq[d] = s + bhh_l[d];
        }
      }
    }
    __syncthreads();

    // ---- gate nonlinearity + h update (verbatim v4 formulas) --------------
    float hnew = 0.f;
    if (tid < Hn) {
      const int j = tid;
      int tk = s_tok;
      if ((unsigned)tk > 32u) tk = 0;  // defensive clamp
      const float giR = GEM[tk * 1536 + j];
      const float giZ = GEM[tk * 1536 + 512 + j];
      const float giN = GEM[tk * 1536 + 1024 + j];
      const float rr = 1.f / (1.f + expf(-(giR + ghq[j])));
      const float zz = 1.f / (1.f + expf(-(giZ + ghq[512 + j])));
      const float nn = tanhf(giN + rr * ghq[1024 + j]);
      const float hv = h_l[j];
      hnew = (1.f - zz) * nn + zz * hv;
    }
    __syncthreads();
    if (tid < Hn) h_l[tid] = hnew;
    __syncthreads();

    // ---- attention: p = memW^T h_new (v4 order; batched via unroll) -------
    {
      const int u = tid & 127, c8 = tid >> 7;
      float a = 0.f;
      if (mode) {
        const u16* mw = (const u16*)memW + u;
#pragma unroll 8
        for (int k = c8 * 64; k < c8 * 64 + 64; k++)
          a = fmaf(b2f(mw[(size_t)k * UDn]), h_l[k], a);
      } else {
        const float* mw = (const float*)memW + u;
#pragma unroll 8
        for (int k = c8 * 64; k < c8 * 64 + 64; k++)
          a = fmaf(mw[(size_t)k * UDn], h_l[k], a);
      }
      Bpart[c8 * UDn + u] = a;
    }
    __syncthreads();
    if (tid < 128) {
      float s = 0.f;
#pragma unroll
      for (int c = 0; c < 8; c++) s += Bpart[c * UDn + tid];
      ps[tid] = s;
    } else if (tid < 192) {  // s0 = h_new . mem_b
      const int ln = tid - 128;
      float a = 0.f;
#pragma unroll
      for (int i = 0; i < 8; i++) { int k = ln + i * 64; a = fmaf(h_l[k], ldv(memb, k, mode), a); }
      for (int o = 32; o; o >>= 1) a += __shfl_down(a, o);
      if (ln == 0) misc_l[0] = a;
    }
    __syncthreads();

    // ---- scores[l] = p . ul[l] + s0 (verbatim v4) -------------------------
    {
      const int l = (wv << 5) + (lane >> 1), uh = lane & 1;
      float val = 0.f;
      if (l < Ln) {
        if (mode) {
          const u32* q = (const u32*)ulat_l + l * 65 + uh * 32;
          for (int i = 0; i < 32; i++) {
            const u32 d = q[i];
            val = fmaf(bitsf(d << 16), ps[uh * 64 + i * 2], val);
            val = fmaf(bitsf(d & 0xffff0000u), ps[uh * 64 + i * 2 + 1], val);
          }
        } else {
          const float* q = (const float*)ulat + ((size_t)blk * Ln + l) * UDn + uh * 64;
          for (int i = 0; i < 64; i++) val = fmaf(q[i], ps[uh * 64 + i], val);
        }
      }
      const float v2v = __shfl_down(val, 1);
      if ((lane & 1) == 0 && l < Ln) ss[l] = val + v2v + misc_l[0];
    }
    __syncthreads();
    if (wv == 0) {  // softmax stats over 500 (verbatim)
      float mx = -3.4e38f;
      for (int i = 0; i < 8; i++) {
        int l = lane + (i << 6);
        if (l < Ln) mx = fmaxf(mx, ss[l]);
      }
      for (int o = 32; o; o >>= 1) mx = fmaxf(mx, __shfl_xor(mx, o));
      float sum = 0.f;
      for (int i = 0; i < 8; i++) {
        int l = lane + (i << 6);
        if (l < Ln) { float e = expf(ss[l] - mx); es[l] = e; sum += e; }
      }
      for (int o = 32; o; o >>= 1) sum += __shfl_xor(sum, o);
      if (lane == 0) misc_l[1] = 1.f / sum;
    }
    __syncthreads();

    // ---- cu[u] = inv * sum_l es[l] * ul[l][u] (v4 order, unroll-batched) --
    {
      const int u = tid & 127, lc = tid >> 7;
      const int lend = (lc * 64 + 64 < Ln) ? lc * 64 + 64 : Ln;
      float a = 0.f;
      if (mode) {
#pragma unroll 8
        for (int l = lc * 64; l < lend; l++) a = fmaf(es[l], b2f(ulat_l[l * 130 + u]), a);
      } else {
        const float* q = (const float*)ulat + ((size_t)blk * Ln) * UDn + u;
#pragma unroll 8
        for (int l = lc * 64; l < lend; l++) a = fmaf(es[l], q[(size_t)l * UDn], a);
      }
      Bpart[lc * UDn + u] = a;
    }
    __syncthreads();
    if (tid < 128) {
      float s = 0.f;
#pragma unroll
      for (int c = 0; c < 8; c++) s += Bpart[c * UDn + tid];
      cuv[tid] = s * misc_l[1];
    }
    __syncthreads();

    // ---- cc = tanh(catWl.h + M2.cu + cbias) (v4-exact chain, batched) -----
    {
      const int j = tid & 511, hf = tid >> 9;
      float a = 0.f;
      if (mode) {
        const u4* cw = (const u4*)((const u16*)catW + (size_t)j * 1024) + hf * 32;
#pragma unroll
        for (int b2 = 0; b2 < 4; b2++) {
          u4 q[8];
#pragma unroll
          for (int s2 = 0; s2 < 8; s2++) q[s2] = cw[b2 * 8 + s2];
#pragma unroll
          for (int s2 = 0; s2 < 8; s2++) {
            const int e = hf * 256 + b2 * 64 + s2 * 8;
            const f4 xa = *(const f4*)(h_l + e), xb = *(const f4*)(h_l + e + 4);
            a = fmaf(LO16(q[s2].x), xa.x, a); a = fmaf(HI16(q[s2].x), xa.y, a);
            a = fmaf(LO16(q[s2].y), xa.z, a); a = fmaf(HI16(q[s2].y), xa.w, a);
            a = fmaf(LO16(q[s2].z), xb.x, a); a = fmaf(HI16(q[s2].z), xb.y, a);
            a = fmaf(LO16(q[s2].w), xb.z, a); a = fmaf(HI16(q[s2].w), xb.w, a);
          }
        }
      } else {
        const f4* cw4 = (const f4*)catW + (size_t)j * 256 + hf * 64;
#pragma unroll
        for (int b2 = 0; b2 < 8; b2++) {
          f4 q[8];
#pragma unroll
          for (int s2 = 0; s2 < 8; s2++) q[s2] = cw4[b2 * 8 + s2];
#pragma unroll
          for (int s2 = 0; s2 < 8; s2++) {
            const int e = hf * 256 + b2 * 32 + s2 * 4;
            const f4 xa = *(const f4*)(h_l + e);
            a = fmaf(q[s2].x, xa.x, a); a = fmaf(q[s2].y, xa.y, a);
            a = fmaf(q[s2].z, xa.z, a); a = fmaf(q[s2].w, xa.w, a);
          }
        }
      }
      {  // M2 part (f32, ascending — v4-exact)
        const f4* m2 = (const f4*)(M2 + (size_t)j * 128) + hf * 16;
#pragma unroll
        for (int b2 = 0; b2 < 2; b2++) {
          f4 q[8];
#pragma unroll
          for (int s2 = 0; s2 < 8; s2++) q[s2] = m2[b2 * 8 + s2];
#pragma unroll
          for (int s2 = 0; s2 < 8; s2++) {
            const int e = hf * 64 + b2 * 32 + s2 * 4;
            const f4 xc = *(const f4*)(cuv + e);
            a = fmaf(q[s2].x, xc.x, a); a = fmaf(q[s2].y, xc.y, a);
            a = fmaf(q[s2].z, xc.z, a); a = fmaf(q[s2].w, xc.w, a);
          }
        }
      }
      ccp2[j * 2 + hf] = a;
    }
    __syncthreads();
    if (tid < Hn)
      ccs[tid] = tanhf(ccp2[tid * 2] + ccp2[tid * 2 + 1] + cbF[tid]);
    __syncthreads();

    // ---- logits + argmax + output (verbatim v4) ---------------------------
    if (lane < Vn) {
      const int j0 = wv << 5;
      float part = 0.f;
#pragma unroll
      for (int q = 0; q < 32; q++)
        part = fmaf(ccs[j0 + q], ldv(outW, (size_t)lane * Hn + j0 + q, mode), part);
      lgs[wv * 34 + lane] = part;
    }
    __syncthreads();
    if (wv == 0) {
      float lg = -3.4e38f;
      int idx = 0;
      if (lane < Vn) {
        float s = (lane < Vn) ? ldv(outb, lane, mode) : 0.f;
#pragma unroll
        for (int w2 = 0; w2 < 16; w2++) s += lgs[w2 * 34 + lane];
        if (mode) ((u16*)out)[(size_t)blk * (Vn * Ln) + lane * Ln + t] = f2b(s);
        else ((float*)out)[(size_t)blk * (Vn * Ln) + lane * Ln + t] = s;
        lg = s;
        idx = lane;
      }
      for (int o = 32; o; o >>= 1) {  // np argmax: first max wins
        const float ov = __shfl_down(lg, o);
        const int oi = __shfl_down(idx, o);
        if (ov > lg || (ov == lg && oi < idx)) { lg = ov; idx = oi; }
      }
      if (lane == 0) s_tok = idx;
    }
  }
}

extern "C" void kernel_launch(void* const* d_in, const int* in_sizes, int n_in,
                              void* d_out, int out_size, void* d_ws, size_t ws_size,
                              hipStream_t stream) {
  (void)in_sizes; (void)n_in; (void)out_size;
  if (ws_size < (size_t)W_END * 4) return;  // needs ~0.5 MB scratch
  hipLaunchKernelGGL(rnn_v6, dim3(NB), dim3(NT), 0, stream,
                     d_in[0],   // latent
                     d_in[1],   // upsampled_latent
                     d_in[3],   // embed (d_in[2]=target unused in eval)
                     d_in[4],   // hid_W
                     d_in[5],   // hid_b
                     d_in[6],   // mem_W
                     d_in[7],   // mem_b
                     d_in[8],   // W_ih
                     d_in[9],   // W_hh
                     d_in[10],  // b_ih
                     d_in[11],  // b_hh
                     d_in[12],  // cat_W
                     d_in[13],  // cat_b
                     d_in[14],  // out_W
                     d_in[15],  // out_b
                     d_out, (u32*)d_ws);
}